// Round 1
// 140.559 us; speedup vs baseline: 1.1772x; 1.1772x over previous
//
#include <hip/hip_runtime.h>

constexpr int N_  = 10000;
constexpr int F_  = 128;
constexpr int E_  = 160000;
constexpr int BT_ = 4;            // B*T
constexpr int M_  = N_ * BT_;     // 40000 rows of [F]
constexpr int CAP = 64;           // bucket capacity per node (deg ~ Poisson(16))

typedef __attribute__((ext_vector_type(8))) short bf16x8;   // 8 bf16 in 4 VGPRs
typedef __attribute__((ext_vector_type(4))) float f32x4;
typedef __attribute__((ext_vector_type(2))) float f32x2;
typedef __attribute__((ext_vector_type(8))) unsigned short u16x8;

static __device__ inline float bf2f(unsigned short u) {
    union { unsigned int i; float f; } v; v.i = ((unsigned int)u) << 16; return v.f;
}
static __device__ inline unsigned short f2bf(float f) {
    union { float f; unsigned int i; } v; v.f = f;
    unsigned int x = v.i;
    return (unsigned short)((x + 0x7fffu + ((x >> 16) & 1u)) >> 16);  // RNE
}

// ---------- fused prep: edge-scatter + weight-pack + transpose ----------
// blocks [0,625):    scatter edges into fixed-capacity buckets (count fused)
// blocks [625,657):  pack W into MFMA B-fragment layout (+ zero dummy rows)
// blocks [657,5657): transpose [B,T,N,F] fp32 -> [N*BT,F] bf16 + fp8 shadow

__global__ __launch_bounds__(256) void k_pre(const float4* __restrict__ feat,
        unsigned short* __restrict__ h0, unsigned char* __restrict__ h8,
        unsigned char* __restrict__ h18z,
        const int* __restrict__ src, const int* __restrict__ dst,
        int* __restrict__ cursor, int* __restrict__ bucket,
        const float* __restrict__ Wself, const float* __restrict__ Wneigh,
        unsigned short* __restrict__ Wp) {
    const int b = blockIdx.x;
    const int tid = threadIdx.x;
    if (b < 625) {
        int e = b * 256 + tid;           // E_ == 625*256 exactly
        int d = dst[e];
        int p = atomicAdd(&cursor[d], 1);
        if (p < CAP) bucket[d * CAP + p] = src[e];
    } else if (b < 657) {
        // zero the dummy node row (index N_) of both fp8 shadow tables; the
        // workspace is re-poisoned by the harness each iteration, so this must
        // be re-zeroed here every launch.
        if (b == 625) {
            if (tid < 64) {
                uint2 z; z.x = 0u; z.y = 0u;
                *(uint2*)(h8 + (size_t)N_ * 512 + tid * 8) = z;
            } else if (tid < 128) {
                uint2 z; z.x = 0u; z.y = 0u;
                *(uint2*)(h18z + (size_t)N_ * 512 + (tid - 64) * 8) = z;
            }
        }
        int t = (b - 625) * 256 + tid;
        int mat = t >> 11;
        int r = t & 2047;
        int kb = r >> 9;
        int nb = (r >> 6) & 7;
        int lane = r & 63;
        int l = mat >> 1, s = mat & 1;
        const float* W = (s ? Wneigh : Wself) + (size_t)l * F_ * F_;
        int k0 = kb * 32 + (lane >> 4) * 8;
        int n  = nb * 16 + (lane & 15);
        unsigned short* dstp = Wp + (size_t)mat * 16384 +
                               (size_t)((kb * 8 + nb) * 64 + lane) * 8;
#pragma unroll
        for (int j = 0; j < 8; j++) dstp[j] = f2bf(W[(size_t)(k0 + j) * F_ + n]);
    } else {
        int i = (b - 657) * 256 + tid;   // over M_*32 float4s
        int f4 = i & 31;
        int m  = i >> 5;                 // m = n*BT_ + bt
        int n  = m >> 2;
        int bt = m & 3;
        float4 v = feat[(bt * N_ + n) * 32 + f4];
        ushort4 o;
        o.x = f2bf(v.x); o.y = f2bf(v.y); o.z = f2bf(v.z); o.w = f2bf(v.w);
        *(ushort4*)(h0 + (size_t)m * 128 + f4 * 4) = o;
        // fp8 e4m3 shadow for layer-0 gather (RNE hw converter)
        int w0 = __builtin_amdgcn_cvt_pk_fp8_f32(v.x, v.y, 0, false);
        int w1 = __builtin_amdgcn_cvt_pk_fp8_f32(v.z, v.w, w0, true);
        *(unsigned int*)(h8 + (size_t)m * 128 + f4 * 4) = (unsigned int)w1;
    }
}

// ---------- fused layer: per-wave fp8 aggregation (LDS) + double-MFMA GEMM --
// Block = 2 waves x 16 rows = 8 nodes; 1250 blocks (grid-capped at ~2.44
// waves/SIMD, so latency hiding must come from MLP within the wave).
// Phase A: the 4 node chains (cursor -> bucket -> gather batches) are
// INTERLEAVED, padded branch-free to max degree with the zeroed dummy row
// (node N_). fp8 zero decodes to 0.0f, so padding doesn't perturb sums and
// per-node accumulation order is unchanged (bit-identical numerics).

template <bool LAST>
__global__ __launch_bounds__(128) void k_fused(const unsigned short* __restrict__ h,
        const unsigned char* __restrict__ g8, unsigned char* __restrict__ s8out,
        const int* __restrict__ cursor, const int* __restrict__ bucket,
        const unsigned short* __restrict__ Wp, const float* __restrict__ bias,
        void* __restrict__ outv) {
    // [wave][node_local][bt][128+8] — pad keeps ds_read_b128 bank-uniform
    __shared__ unsigned short aggs[2][4][4][136];
    const int tid  = threadIdx.x;
    const int wave = tid >> 6, lane = tid & 63;
    const int m0   = blockIdx.x * 32 + wave * 16;
    const int node0 = m0 >> 2;
    const int col  = lane & 15;
    const int quad = lane >> 4;

    // ---- hoisted A-fragment loads (independent of the gather; fly under it)
    const unsigned short* A0 = h + (size_t)(m0 + col) * 128 + quad * 8;
    bf16x8 aA[4];
#pragma unroll
    for (int kb = 0; kb < 4; kb++) aA[kb] = *(const bf16x8*)(A0 + kb * 32);

    // ---- phase A: aggregate 4 nodes (fp8 gather), chains interleaved ----
    int deg_[4], nn_[4], idx_[4];
#pragma unroll
    for (int nl = 0; nl < 4; nl++) deg_[nl] = cursor[node0 + nl];
#pragma unroll
    for (int nl = 0; nl < 4; nl++) {
        nn_[nl] = deg_[nl] < CAP ? deg_[nl] : CAP;
        idx_[nl] = bucket[(node0 + nl) * CAP + (lane < nn_[nl] ? lane : 0)];
    }
    int mx = nn_[0];
    mx = nn_[1] > mx ? nn_[1] : mx;
    mx = nn_[2] > mx ? nn_[2] : mx;
    mx = nn_[3] > mx ? nn_[3] : mx;

    float acc4[4][8] = {{0.f, 0.f, 0.f, 0.f, 0.f, 0.f, 0.f, 0.f},
                        {0.f, 0.f, 0.f, 0.f, 0.f, 0.f, 0.f, 0.f},
                        {0.f, 0.f, 0.f, 0.f, 0.f, 0.f, 0.f, 0.f},
                        {0.f, 0.f, 0.f, 0.f, 0.f, 0.f, 0.f, 0.f}};
#pragma unroll 4
    for (int e = 0; e < mx; e++) {
#pragma unroll
        for (int nl = 0; nl < 4; nl++) {
            // wave-uniform select; dead edges read the zeroed dummy row
            int s = (e < nn_[nl]) ? __builtin_amdgcn_readlane(idx_[nl], e) : N_;
            uint2 a8 = *(const uint2*)(g8 + (size_t)s * 512 + lane * 8);
            f32x2 p0 = __builtin_amdgcn_cvt_pk_f32_fp8(a8.x, false);
            f32x2 p1 = __builtin_amdgcn_cvt_pk_f32_fp8(a8.x, true);
            f32x2 p2 = __builtin_amdgcn_cvt_pk_f32_fp8(a8.y, false);
            f32x2 p3 = __builtin_amdgcn_cvt_pk_f32_fp8(a8.y, true);
            acc4[nl][0] += p0.x; acc4[nl][1] += p0.y;
            acc4[nl][2] += p1.x; acc4[nl][3] += p1.y;
            acc4[nl][4] += p2.x; acc4[nl][5] += p2.y;
            acc4[nl][6] += p3.x; acc4[nl][7] += p3.y;
        }
    }
#pragma unroll
    for (int nl = 0; nl < 4; nl++) {
        float w = (deg_[nl] > 0) ? 1.0f / (float)deg_[nl] : 0.0f;
        u16x8 o;
#pragma unroll
        for (int j = 0; j < 8; j++) o[j] = f2bf(acc4[nl][j] * w);
        // lane covers (bt = lane>>4, f = (lane&15)*8 .. +8)
        *(u16x8*)&aggs[wave][nl][lane >> 4][(lane & 15) * 8] = o;
    }

    // ---- phase B: double GEMM (wave-private LDS patch -> no barrier) ----
    f32x4 acc[8];
#pragma unroll
    for (int nb = 0; nb < 8; nb++) {
        float b = bias[nb * 16 + col];
        acc[nb] = (f32x4){b, b, b, b};
    }

    const unsigned short* As = &aggs[wave][col >> 2][col & 3][quad * 8];
    const unsigned short* B0 = Wp + (size_t)lane * 8;
    const unsigned short* B1 = B0 + 16384;

#pragma unroll
    for (int kb = 0; kb < 4; kb++) {
        bf16x8 a = aA[kb];
#pragma unroll
        for (int nb = 0; nb < 8; nb++) {
            bf16x8 b = *(const bf16x8*)(B0 + (size_t)((kb * 8 + nb) * 64) * 8);
            acc[nb] = __builtin_amdgcn_mfma_f32_16x16x32_bf16(a, b, acc[nb], 0, 0, 0);
        }
    }
#pragma unroll
    for (int kb = 0; kb < 4; kb++) {
        bf16x8 a = *(const bf16x8*)(As + kb * 32);   // LDS
#pragma unroll
        for (int nb = 0; nb < 8; nb++) {
            bf16x8 b = *(const bf16x8*)(B1 + (size_t)((kb * 8 + nb) * 64) * 8);
            acc[nb] = __builtin_amdgcn_mfma_f32_16x16x32_bf16(a, b, acc[nb], 0, 0, 0);
        }
    }

    if (LAST) {
        float* out = (float*)outv;
#pragma unroll
        for (int nb = 0; nb < 8; nb++) {
#pragma unroll
            for (int r = 0; r < 4; r++) {
                int m = m0 + quad * 4 + r;
                int node = m >> 2, bt = m & 3;
                out[((size_t)bt * N_ + node) * 128 + nb * 16 + col] = acc[nb][r];
            }
        }
    } else {
        unsigned short* out = (unsigned short*)outv;
#pragma unroll
        for (int nb = 0; nb < 8; nb++) {
#pragma unroll
            for (int r = 0; r < 4; r++) {
                int m = m0 + quad * 4 + r;
                out[(size_t)m * 128 + nb * 16 + col] = f2bf(acc[nb][r]);
                // fp8 shadow of h1 for the layer-1 gather
                int p = __builtin_amdgcn_cvt_pk_fp8_f32(acc[nb][r], acc[nb][r],
                                                        0, false);
                s8out[(size_t)m * 128 + nb * 16 + col] = (unsigned char)(p & 0xff);
            }
        }
    }
}

// ---------------- launch ----------------

extern "C" void kernel_launch(void* const* d_in, const int* in_sizes, int n_in,
                              void* d_out, int out_size, void* d_ws, size_t ws_size,
                              hipStream_t stream) {
    const float* feature = (const float*)d_in[0];   // [B,T,N,F]
    const float* W_self  = (const float*)d_in[1];   // [L,F,F]
    const float* W_neigh = (const float*)d_in[2];   // [L,F,F]
    const float* bias    = (const float*)d_in[3];   // [L,F]
    const int*   e_src   = (const int*)d_in[4];     // [E]
    const int*   e_dst   = (const int*)d_in[5];     // [E]
    float*       out     = (float*)d_out;           // [B,T,N,F]

    char* ws = (char*)d_ws;
    unsigned short* h0   = (unsigned short*)ws;  ws += (size_t)M_ * F_ * 2;   // 10.24 MB
    unsigned short* h1   = (unsigned short*)ws;  ws += (size_t)M_ * F_ * 2;
    unsigned char*  h08  = (unsigned char*)ws;   ws += (size_t)M_ * F_ + 512; // + dummy row
    unsigned char*  h18  = (unsigned char*)ws;   ws += (size_t)M_ * F_ + 512; // + dummy row
    unsigned short* Wp   = (unsigned short*)ws;  ws += (size_t)4 * 16384 * 2; // 128 KB
    int*   cursor  = (int*)ws;                   ws += (size_t)N_ * 4;
    int*   bucket  = (int*)ws;                   ws += (size_t)N_ * CAP * 4;  // 2.56 MB

    hipMemsetAsync(cursor, 0, (size_t)N_ * 4, stream);

    k_pre<<<5657, 256, 0, stream>>>((const float4*)feature, h0, h08, h18, e_src,
                                    e_dst, cursor, bucket, W_self, W_neigh, Wp);

    const int gb = M_ / 32;               // 1250
    // layer 0: fp8 gather from h08; writes h1 (bf16) + h18 (fp8 shadow)
    k_fused<false><<<gb, 128, 0, stream>>>(h0, h08, h18, cursor, bucket, Wp,
                                           bias, h1);
    // layer 1: fp8 gather from h18; writes fp32 out
    k_fused<true><<<gb, 128, 0, stream>>>(h1, h18, nullptr, cursor, bucket,
                                          Wp + 2 * 16384, bias + F_, out);
}

// Round 2
// 139.753 us; speedup vs baseline: 1.1840x; 1.0058x over previous
//
#include <hip/hip_runtime.h>

constexpr int N_  = 10000;
constexpr int F_  = 128;
constexpr int E_  = 160000;
constexpr int BT_ = 4;            // B*T
constexpr int M_  = N_ * BT_;     // 40000 rows of [F]
constexpr int CAP = 64;           // bucket capacity per node (deg ~ Poisson(16))

typedef __attribute__((ext_vector_type(8))) short bf16x8;   // 8 bf16 in 4 VGPRs
typedef __attribute__((ext_vector_type(4))) float f32x4;
typedef __attribute__((ext_vector_type(2))) float f32x2;
typedef __attribute__((ext_vector_type(8))) unsigned short u16x8;

static __device__ inline unsigned short f2bf(float f) {
    union { float f; unsigned int i; } v; v.f = f;
    unsigned int x = v.i;
    return (unsigned short)((x + 0x7fffu + ((x >> 16) & 1u)) >> 16);  // RNE
}

// ---------- fused prep: edge-scatter + weight-pack + transpose ----------
// blocks [0,625):    scatter edges into fixed-capacity buckets (count fused)
// blocks [625,657):  pack W into MFMA B-fragment layout (+ zero dummy rows)
// blocks [657,5657): transpose [B,T,N,F] fp32 -> [N*BT,F] bf16 + fp8 shadow

__global__ __launch_bounds__(256) void k_pre(const float4* __restrict__ feat,
        unsigned short* __restrict__ h0, unsigned char* __restrict__ h8,
        unsigned char* __restrict__ h18z,
        const int* __restrict__ src, const int* __restrict__ dst,
        int* __restrict__ cursor, int* __restrict__ bucket,
        const float* __restrict__ Wself, const float* __restrict__ Wneigh,
        unsigned short* __restrict__ Wp) {
    const int b = blockIdx.x;
    const int tid = threadIdx.x;
    if (b < 625) {
        int e = b * 256 + tid;           // E_ == 625*256 exactly
        int d = dst[e];
        int p = atomicAdd(&cursor[d], 1);
        if (p < CAP) bucket[d * CAP + p] = src[e];
    } else if (b < 657) {
        // zero the dummy node row (index N_) of both fp8 shadow tables; the
        // workspace is re-poisoned by the harness each iteration, so this must
        // be re-zeroed here every launch. (Gather loops pad to a multiple of 8
        // edges with reads of this row; fp8 zero decodes to 0.0f.)
        if (b == 625) {
            if (tid < 64) {
                uint2 z; z.x = 0u; z.y = 0u;
                *(uint2*)(h8 + (size_t)N_ * 512 + tid * 8) = z;
            } else if (tid < 128) {
                uint2 z; z.x = 0u; z.y = 0u;
                *(uint2*)(h18z + (size_t)N_ * 512 + (tid - 64) * 8) = z;
            }
        }
        int t = (b - 625) * 256 + tid;
        int mat = t >> 11;
        int r = t & 2047;
        int kb = r >> 9;
        int nb = (r >> 6) & 7;
        int lane = r & 63;
        int l = mat >> 1, s = mat & 1;
        const float* W = (s ? Wneigh : Wself) + (size_t)l * F_ * F_;
        int k0 = kb * 32 + (lane >> 4) * 8;
        int n  = nb * 16 + (lane & 15);
        unsigned short* dstp = Wp + (size_t)mat * 16384 +
                               (size_t)((kb * 8 + nb) * 64 + lane) * 8;
#pragma unroll
        for (int j = 0; j < 8; j++) dstp[j] = f2bf(W[(size_t)(k0 + j) * F_ + n]);
    } else {
        int i = (b - 657) * 256 + tid;   // over M_*32 float4s
        int f4 = i & 31;
        int m  = i >> 5;                 // m = n*BT_ + bt
        int n  = m >> 2;
        int bt = m & 3;
        float4 v = feat[(bt * N_ + n) * 32 + f4];
        ushort4 o;
        o.x = f2bf(v.x); o.y = f2bf(v.y); o.z = f2bf(v.z); o.w = f2bf(v.w);
        *(ushort4*)(h0 + (size_t)m * 128 + f4 * 4) = o;
        // fp8 e4m3 shadow for layer-0 gather (RNE hw converter)
        int w0 = __builtin_amdgcn_cvt_pk_fp8_f32(v.x, v.y, 0, false);
        int w1 = __builtin_amdgcn_cvt_pk_fp8_f32(v.z, v.w, w0, true);
        *(unsigned int*)(h8 + (size_t)m * 128 + f4 * 4) = (unsigned int)w1;
    }
}

// ---------- fused layer: per-wave fp8 aggregation (LDS) + double-MFMA GEMM --
// Block = 4 waves x 16 rows = 4 nodes; 2500 blocks -> 10000 waves (~4x the
// TLP of the previous 2-wave/4-node design; phase-A serial chain is 1 node
// deep instead of 4).
// Phase A: wave w gathers node (node0 + w); edge loop is padded branch-free
// to a multiple of 8 with the zeroed dummy row (node N_), so there is never
// a serial scalar remainder. fp8 zero decodes to 0.0 and per-node
// accumulation order is unchanged -> bit-identical numerics.
// Phase B: after one barrier, the 4 waves split the N dimension (2 of 8
// nb-blocks each) over the same 16 rows.

template <bool LAST>
__global__ __launch_bounds__(256) void k_fused(const unsigned short* __restrict__ h,
        const unsigned char* __restrict__ g8, unsigned char* __restrict__ s8out,
        const int* __restrict__ cursor, const int* __restrict__ bucket,
        const unsigned short* __restrict__ Wp, const float* __restrict__ bias,
        void* __restrict__ outv) {
    // [node_local][bt][128+8] — pad keeps ds_read_b128 bank spread
    __shared__ unsigned short aggs[4][4][136];
    const int tid  = threadIdx.x;
    const int wave = tid >> 6, lane = tid & 63;
    const int m0   = blockIdx.x * 16;     // 16 rows = 4 nodes per block
    const int node0 = m0 >> 2;
    const int col  = lane & 15;
    const int quad = lane >> 4;

    // ---- hoisted A-fragment loads (independent of the gather; fly under it)
    const unsigned short* A0 = h + (size_t)(m0 + col) * 128 + quad * 8;
    bf16x8 aA[4];
#pragma unroll
    for (int kb = 0; kb < 4; kb++) aA[kb] = *(const bf16x8*)(A0 + kb * 32);

    // ---- phase A: this wave aggregates node (node0 + wave) ----
    const int n   = node0 + wave;
    const int deg = cursor[n];
    const int nn  = deg < CAP ? deg : CAP;
    const int nn8 = (nn + 7) & ~7;        // padded with dummy-row reads
    int idx = bucket[n * CAP + (lane < nn ? lane : 0)];   // coalesced preload

    float acc8[8] = {0.f, 0.f, 0.f, 0.f, 0.f, 0.f, 0.f, 0.f};
    for (int e0 = 0; e0 < nn8; e0 += 8) {
#pragma unroll
        for (int u = 0; u < 8; u++) {
            int e = e0 + u;
            // wave-uniform select; dead edges read the zeroed dummy row
            int s = (e < nn) ? __builtin_amdgcn_readlane(idx, e) : N_;
            uint2 a8 = *(const uint2*)(g8 + (size_t)s * 512 + lane * 8);
            f32x2 p0 = __builtin_amdgcn_cvt_pk_f32_fp8(a8.x, false);
            f32x2 p1 = __builtin_amdgcn_cvt_pk_f32_fp8(a8.x, true);
            f32x2 p2 = __builtin_amdgcn_cvt_pk_f32_fp8(a8.y, false);
            f32x2 p3 = __builtin_amdgcn_cvt_pk_f32_fp8(a8.y, true);
            acc8[0] += p0.x; acc8[1] += p0.y;
            acc8[2] += p1.x; acc8[3] += p1.y;
            acc8[4] += p2.x; acc8[5] += p2.y;
            acc8[6] += p3.x; acc8[7] += p3.y;
        }
    }
    {
        float w = (deg > 0) ? 1.0f / (float)deg : 0.0f;
        u16x8 o;
#pragma unroll
        for (int j = 0; j < 8; j++) o[j] = f2bf(acc8[j] * w);
        // lane covers (bt = lane>>4, f = (lane&15)*8 .. +8)
        *(u16x8*)&aggs[wave][lane >> 4][(lane & 15) * 8] = o;
    }
    __syncthreads();

    // ---- phase B: 4 waves split the 8 nb-blocks over the same 16 rows ----
    const int np = wave;                  // nb pair index: nb = np*2, np*2+1
    f32x4 acc[2];
#pragma unroll
    for (int j = 0; j < 2; j++) {
        float b = bias[(np * 2 + j) * 16 + col];
        acc[j] = (f32x4){b, b, b, b};
    }

    const unsigned short* As = &aggs[col >> 2][col & 3][quad * 8];
    const unsigned short* B0 = Wp + (size_t)lane * 8;
    const unsigned short* B1 = B0 + 16384;

#pragma unroll
    for (int kb = 0; kb < 4; kb++) {
        bf16x8 a = aA[kb];
#pragma unroll
        for (int j = 0; j < 2; j++) {
            int nb = np * 2 + j;
            bf16x8 b = *(const bf16x8*)(B0 + (size_t)((kb * 8 + nb) * 64) * 8);
            acc[j] = __builtin_amdgcn_mfma_f32_16x16x32_bf16(a, b, acc[j], 0, 0, 0);
        }
    }
#pragma unroll
    for (int kb = 0; kb < 4; kb++) {
        bf16x8 a = *(const bf16x8*)(As + kb * 32);   // LDS
#pragma unroll
        for (int j = 0; j < 2; j++) {
            int nb = np * 2 + j;
            bf16x8 b = *(const bf16x8*)(B1 + (size_t)((kb * 8 + nb) * 64) * 8);
            acc[j] = __builtin_amdgcn_mfma_f32_16x16x32_bf16(a, b, acc[j], 0, 0, 0);
        }
    }

    if (LAST) {
        float* out = (float*)outv;
#pragma unroll
        for (int j = 0; j < 2; j++) {
            int nb = np * 2 + j;
#pragma unroll
            for (int r = 0; r < 4; r++) {
                int m = m0 + quad * 4 + r;
                int node = m >> 2, bt = m & 3;
                out[((size_t)bt * N_ + node) * 128 + nb * 16 + col] = acc[j][r];
            }
        }
    } else {
        unsigned short* out = (unsigned short*)outv;
#pragma unroll
        for (int j = 0; j < 2; j++) {
            int nb = np * 2 + j;
#pragma unroll
            for (int r = 0; r < 4; r++) {
                int m = m0 + quad * 4 + r;
                out[(size_t)m * 128 + nb * 16 + col] = f2bf(acc[j][r]);
                // fp8 shadow of h1 for the layer-1 gather
                int p = __builtin_amdgcn_cvt_pk_fp8_f32(acc[j][r], acc[j][r],
                                                        0, false);
                s8out[(size_t)m * 128 + nb * 16 + col] = (unsigned char)(p & 0xff);
            }
        }
    }
}

// ---------------- launch ----------------

extern "C" void kernel_launch(void* const* d_in, const int* in_sizes, int n_in,
                              void* d_out, int out_size, void* d_ws, size_t ws_size,
                              hipStream_t stream) {
    const float* feature = (const float*)d_in[0];   // [B,T,N,F]
    const float* W_self  = (const float*)d_in[1];   // [L,F,F]
    const float* W_neigh = (const float*)d_in[2];   // [L,F,F]
    const float* bias    = (const float*)d_in[3];   // [L,F]
    const int*   e_src   = (const int*)d_in[4];     // [E]
    const int*   e_dst   = (const int*)d_in[5];     // [E]
    float*       out     = (float*)d_out;           // [B,T,N,F]

    char* ws = (char*)d_ws;
    unsigned short* h0   = (unsigned short*)ws;  ws += (size_t)M_ * F_ * 2;   // 10.24 MB
    unsigned short* h1   = (unsigned short*)ws;  ws += (size_t)M_ * F_ * 2;
    unsigned char*  h08  = (unsigned char*)ws;   ws += (size_t)M_ * F_ + 512; // + dummy row
    unsigned char*  h18  = (unsigned char*)ws;   ws += (size_t)M_ * F_ + 512; // + dummy row
    unsigned short* Wp   = (unsigned short*)ws;  ws += (size_t)4 * 16384 * 2; // 128 KB
    int*   cursor  = (int*)ws;                   ws += (size_t)N_ * 4;
    int*   bucket  = (int*)ws;                   ws += (size_t)N_ * CAP * 4;  // 2.56 MB

    hipMemsetAsync(cursor, 0, (size_t)N_ * 4, stream);

    k_pre<<<5657, 256, 0, stream>>>((const float4*)feature, h0, h08, h18, e_src,
                                    e_dst, cursor, bucket, W_self, W_neigh, Wp);

    const int gb = M_ / 16;               // 2500 blocks, 4 waves each
    // layer 0: fp8 gather from h08; writes h1 (bf16) + h18 (fp8 shadow)
    k_fused<false><<<gb, 256, 0, stream>>>(h0, h08, h18, cursor, bucket, Wp,
                                           bias, h1);
    // layer 1: fp8 gather from h18; writes fp32 out
    k_fused<true><<<gb, 256, 0, stream>>>(h1, h18, nullptr, cursor, bucket,
                                          Wp + 2 * 16384, bias + F_, out);
}

// Round 3
// 139.310 us; speedup vs baseline: 1.1877x; 1.0032x over previous
//
#include <hip/hip_runtime.h>

constexpr int N_  = 10000;
constexpr int F_  = 128;
constexpr int E_  = 160000;
constexpr int BT_ = 4;            // B*T
constexpr int M_  = N_ * BT_;     // 40000 rows of [F]
constexpr int CAP = 64;           // bucket capacity per node (deg ~ Poisson(16))

typedef __attribute__((ext_vector_type(8))) short bf16x8;   // 8 bf16 in 4 VGPRs
typedef __attribute__((ext_vector_type(4))) float f32x4;
typedef __attribute__((ext_vector_type(2))) float f32x2;
typedef __attribute__((ext_vector_type(8))) unsigned short u16x8;

union bfu { u16x8 u; bf16x8 s; };

static __device__ inline unsigned short f2bf(float f) {
    union { float f; unsigned int i; } v; v.f = f;
    unsigned int x = v.i;
    return (unsigned short)((x + 0x7fffu + ((x >> 16) & 1u)) >> 16);  // RNE
}

// ---------- fused prep: edge-scatter + weight-pack + fp8 shadow ----------
// blocks [0,625):      scatter edges into fixed-capacity buckets (count fused)
// blocks [625,657):    pack W into MFMA B-fragment layout (+ zero dummy rows)
// blocks [657,3157):   [B,T,N,F] fp32 -> [N*BT,F] fp8 shadow (32 B/lane)
// NOTE: no bf16 h0 staging anymore — layer 0's A-fragments are built
// in-register inside k_fused from the fp32 feature (same RNE cvt ->
// bit-identical MFMA inputs), saving a 10.24 MB write + read.

__global__ __launch_bounds__(256) void k_pre(const float4* __restrict__ feat,
        unsigned char* __restrict__ h8, unsigned char* __restrict__ h18z,
        const int* __restrict__ src, const int* __restrict__ dst,
        int* __restrict__ cursor, int* __restrict__ bucket,
        const float* __restrict__ Wself, const float* __restrict__ Wneigh,
        unsigned short* __restrict__ Wp) {
    const int b = blockIdx.x;
    const int tid = threadIdx.x;
    if (b < 625) {
        int e = b * 256 + tid;           // E_ == 625*256 exactly
        int d = dst[e];
        int p = atomicAdd(&cursor[d], 1);
        if (p < CAP) bucket[d * CAP + p] = src[e];
    } else if (b < 657) {
        // zero the dummy node row (index N_) of both fp8 shadow tables; the
        // workspace is re-poisoned by the harness each iteration, so this must
        // be re-zeroed here every launch. (Gather loops pad to a multiple of 4
        // edges with reads of this row; fp8 zero decodes to 0.0f.)
        if (b == 625) {
            if (tid < 64) {
                uint2 z; z.x = 0u; z.y = 0u;
                *(uint2*)(h8 + (size_t)N_ * 512 + tid * 8) = z;
            } else if (tid < 128) {
                uint2 z; z.x = 0u; z.y = 0u;
                *(uint2*)(h18z + (size_t)N_ * 512 + (tid - 64) * 8) = z;
            }
        }
        int t = (b - 625) * 256 + tid;
        int mat = t >> 11;
        int r = t & 2047;
        int kb = r >> 9;
        int nb = (r >> 6) & 7;
        int lane = r & 63;
        int l = mat >> 1, s = mat & 1;
        const float* W = (s ? Wneigh : Wself) + (size_t)l * F_ * F_;
        int k0 = kb * 32 + (lane >> 4) * 8;
        int n  = nb * 16 + (lane & 15);
        unsigned short* dstp = Wp + (size_t)mat * 16384 +
                               (size_t)((kb * 8 + nb) * 64 + lane) * 8;
#pragma unroll
        for (int j = 0; j < 8; j++) dstp[j] = f2bf(W[(size_t)(k0 + j) * F_ + n]);
    } else {
        int i = (b - 657) * 256 + tid;   // over M_*16 chunks of 8 floats
        int c8 = i & 15;                 // 8-float chunk within the row
        int m  = i >> 4;                 // m = n*BT_ + bt
        int n  = m >> 2;
        int bt = m & 3;
        const float4* p = feat + ((size_t)(bt * N_ + n) * 32 + c8 * 2);
        float4 v0 = p[0];
        float4 v1 = p[1];
        // fp8 e4m3 shadow for layer-0 gather (RNE hw converter)
        int w0 = __builtin_amdgcn_cvt_pk_fp8_f32(v0.x, v0.y, 0, false);
        int w1 = __builtin_amdgcn_cvt_pk_fp8_f32(v0.z, v0.w, w0, true);
        int w2 = __builtin_amdgcn_cvt_pk_fp8_f32(v1.x, v1.y, 0, false);
        int w3 = __builtin_amdgcn_cvt_pk_fp8_f32(v1.z, v1.w, w2, true);
        uint2 o; o.x = (unsigned int)w1; o.y = (unsigned int)w3;
        *(uint2*)(h8 + (size_t)m * 128 + c8 * 8) = o;
    }
}

// ---------- fused layer: per-wave fp8 aggregation (LDS) + double-MFMA GEMM --
// Block = 4 waves x 16 rows = 4 nodes; 2500 blocks -> 10000 waves.
// Phase A: wave w gathers node (node0 + w); edge loop is padded branch-free
// to a multiple of 4 with the zeroed dummy row (node N_) — no serial
// remainder, ~10% padding waste (vs 23% at multiple-of-8). fp8 zero decodes
// to 0.0 and per-node accumulation order is unchanged -> bit-identical.
// Phase B: after one barrier, the 4 waves split the N dimension (2 of 8
// nb-blocks each) over the same 16 rows.
// FP32A (layer 0): A-fragments are loaded from the fp32 feature tensor and
// converted with the same RNE f2bf that previously produced h0 -> identical
// MFMA input bits, no staging buffer.

template <bool FP32A, bool LAST>
__global__ __launch_bounds__(256) void k_fused(const void* __restrict__ hA,
        const unsigned char* __restrict__ g8, unsigned char* __restrict__ s8out,
        const int* __restrict__ cursor, const int* __restrict__ bucket,
        const unsigned short* __restrict__ Wp, const float* __restrict__ bias,
        void* __restrict__ outv) {
    // [node_local][bt][128+8] — pad keeps ds_read_b128 bank spread
    __shared__ unsigned short aggs[4][4][136];
    const int tid  = threadIdx.x;
    const int wave = tid >> 6, lane = tid & 63;
    const int m0   = blockIdx.x * 16;     // 16 rows = 4 nodes per block
    const int node0 = m0 >> 2;
    const int col  = lane & 15;
    const int quad = lane >> 4;

    // ---- hoisted A-fragment loads (independent of the gather; fly under it)
    bf16x8 aA[4];
    if (FP32A) {
        const int m = m0 + col;           // row this lane covers
        const int an = m >> 2, abt = m & 3;
        const float* Af = (const float*)hA +
                          ((size_t)(abt * N_ + an) * 128 + quad * 8);
#pragma unroll
        for (int kb = 0; kb < 4; kb++) {
            float4 u0 = *(const float4*)(Af + kb * 32);
            float4 u1 = *(const float4*)(Af + kb * 32 + 4);
            bfu t;
            t.u[0] = f2bf(u0.x); t.u[1] = f2bf(u0.y);
            t.u[2] = f2bf(u0.z); t.u[3] = f2bf(u0.w);
            t.u[4] = f2bf(u1.x); t.u[5] = f2bf(u1.y);
            t.u[6] = f2bf(u1.z); t.u[7] = f2bf(u1.w);
            aA[kb] = t.s;
        }
    } else {
        const unsigned short* A0 = (const unsigned short*)hA +
                                   (size_t)(m0 + col) * 128 + quad * 8;
#pragma unroll
        for (int kb = 0; kb < 4; kb++) aA[kb] = *(const bf16x8*)(A0 + kb * 32);
    }

    // ---- phase A: this wave aggregates node (node0 + wave) ----
    const int n   = node0 + wave;
    const int deg = cursor[n];
    const int nn  = deg < CAP ? deg : CAP;
    const int nn4 = (nn + 3) & ~3;        // padded with dummy-row reads
    int idx = bucket[n * CAP + (lane < nn ? lane : 0)];   // coalesced preload

    float acc8[8] = {0.f, 0.f, 0.f, 0.f, 0.f, 0.f, 0.f, 0.f};
    for (int e0 = 0; e0 < nn4; e0 += 4) {
#pragma unroll
        for (int u = 0; u < 4; u++) {
            int e = e0 + u;
            // wave-uniform select; dead edges read the zeroed dummy row
            int s = (e < nn) ? __builtin_amdgcn_readlane(idx, e) : N_;
            uint2 a8 = *(const uint2*)(g8 + (size_t)s * 512 + lane * 8);
            f32x2 p0 = __builtin_amdgcn_cvt_pk_f32_fp8(a8.x, false);
            f32x2 p1 = __builtin_amdgcn_cvt_pk_f32_fp8(a8.x, true);
            f32x2 p2 = __builtin_amdgcn_cvt_pk_f32_fp8(a8.y, false);
            f32x2 p3 = __builtin_amdgcn_cvt_pk_f32_fp8(a8.y, true);
            acc8[0] += p0.x; acc8[1] += p0.y;
            acc8[2] += p1.x; acc8[3] += p1.y;
            acc8[4] += p2.x; acc8[5] += p2.y;
            acc8[6] += p3.x; acc8[7] += p3.y;
        }
    }
    {
        float w = (deg > 0) ? 1.0f / (float)deg : 0.0f;
        u16x8 o;
#pragma unroll
        for (int j = 0; j < 8; j++) o[j] = f2bf(acc8[j] * w);
        // lane covers (bt = lane>>4, f = (lane&15)*8 .. +8)
        *(u16x8*)&aggs[wave][lane >> 4][(lane & 15) * 8] = o;
    }
    __syncthreads();

    // ---- phase B: 4 waves split the 8 nb-blocks over the same 16 rows ----
    const int np = wave;                  // nb pair index: nb = np*2, np*2+1
    f32x4 acc[2];
#pragma unroll
    for (int j = 0; j < 2; j++) {
        float b = bias[(np * 2 + j) * 16 + col];
        acc[j] = (f32x4){b, b, b, b};
    }

    const unsigned short* As = &aggs[col >> 2][col & 3][quad * 8];
    const unsigned short* B0 = Wp + (size_t)lane * 8;
    const unsigned short* B1 = B0 + 16384;

#pragma unroll
    for (int kb = 0; kb < 4; kb++) {
        bf16x8 a = aA[kb];
#pragma unroll
        for (int j = 0; j < 2; j++) {
            int nb = np * 2 + j;
            bf16x8 b = *(const bf16x8*)(B0 + (size_t)((kb * 8 + nb) * 64) * 8);
            acc[j] = __builtin_amdgcn_mfma_f32_16x16x32_bf16(a, b, acc[j], 0, 0, 0);
        }
    }
#pragma unroll
    for (int kb = 0; kb < 4; kb++) {
        bf16x8 a = *(const bf16x8*)(As + kb * 32);   // LDS
#pragma unroll
        for (int j = 0; j < 2; j++) {
            int nb = np * 2 + j;
            bf16x8 b = *(const bf16x8*)(B1 + (size_t)((kb * 8 + nb) * 64) * 8);
            acc[j] = __builtin_amdgcn_mfma_f32_16x16x32_bf16(a, b, acc[j], 0, 0, 0);
        }
    }

    if (LAST) {
        float* out = (float*)outv;
#pragma unroll
        for (int j = 0; j < 2; j++) {
            int nb = np * 2 + j;
#pragma unroll
            for (int r = 0; r < 4; r++) {
                int m = m0 + quad * 4 + r;
                int node = m >> 2, bt = m & 3;
                out[((size_t)bt * N_ + node) * 128 + nb * 16 + col] = acc[j][r];
            }
        }
    } else {
        unsigned short* out = (unsigned short*)outv;
#pragma unroll
        for (int j = 0; j < 2; j++) {
            int nb = np * 2 + j;
#pragma unroll
            for (int r = 0; r < 4; r++) {
                int m = m0 + quad * 4 + r;
                out[(size_t)m * 128 + nb * 16 + col] = f2bf(acc[j][r]);
                // fp8 shadow of h1 for the layer-1 gather
                int p = __builtin_amdgcn_cvt_pk_fp8_f32(acc[j][r], acc[j][r],
                                                        0, false);
                s8out[(size_t)m * 128 + nb * 16 + col] = (unsigned char)(p & 0xff);
            }
        }
    }
}

// ---------------- launch ----------------

extern "C" void kernel_launch(void* const* d_in, const int* in_sizes, int n_in,
                              void* d_out, int out_size, void* d_ws, size_t ws_size,
                              hipStream_t stream) {
    const float* feature = (const float*)d_in[0];   // [B,T,N,F]
    const float* W_self  = (const float*)d_in[1];   // [L,F,F]
    const float* W_neigh = (const float*)d_in[2];   // [L,F,F]
    const float* bias    = (const float*)d_in[3];   // [L,F]
    const int*   e_src   = (const int*)d_in[4];     // [E]
    const int*   e_dst   = (const int*)d_in[5];     // [E]
    float*       out     = (float*)d_out;           // [B,T,N,F]

    char* ws = (char*)d_ws;
    unsigned short* h1   = (unsigned short*)ws;  ws += (size_t)M_ * F_ * 2;   // 10.24 MB
    unsigned char*  h08  = (unsigned char*)ws;   ws += (size_t)M_ * F_ + 512; // + dummy row
    unsigned char*  h18  = (unsigned char*)ws;   ws += (size_t)M_ * F_ + 512; // + dummy row
    unsigned short* Wp   = (unsigned short*)ws;  ws += (size_t)4 * 16384 * 2; // 128 KB
    int*   cursor  = (int*)ws;                   ws += (size_t)N_ * 4;
    int*   bucket  = (int*)ws;                   ws += (size_t)N_ * CAP * 4;  // 2.56 MB

    hipMemsetAsync(cursor, 0, (size_t)N_ * 4, stream);

    k_pre<<<3157, 256, 0, stream>>>((const float4*)feature, h08, h18, e_src,
                                    e_dst, cursor, bucket, W_self, W_neigh, Wp);

    const int gb = M_ / 16;               // 2500 blocks, 4 waves each
    // layer 0: A from fp32 feature; fp8 gather from h08; writes h1 + h18
    k_fused<true, false><<<gb, 256, 0, stream>>>(feature, h08, h18, cursor,
                                                 bucket, Wp, bias, h1);
    // layer 1: A from bf16 h1; fp8 gather from h18; writes fp32 out
    k_fused<false, true><<<gb, 256, 0, stream>>>(h1, h18, nullptr, cursor,
                                                 bucket, Wp + 2 * 16384,
                                                 bias + F_, out);
}